// Round 2
// baseline (338.638 us; speedup 1.0000x reference)
//
#include <hip/hip_runtime.h>
#include <stdint.h>

#define S_LEN 4096
#define DMODEL 1024
#define NH 16
#define HDIM 64

typedef __attribute__((ext_vector_type(8))) __bf16 bf16x8;
typedef __attribute__((ext_vector_type(4))) __bf16 bf16x4;
typedef __attribute__((ext_vector_type(4))) float f32x4;

// ---------------- f32 -> bf16 pack (vectorized) -------------------------------
__global__ __launch_bounds__(256) void convert_f32_bf16(const float* __restrict__ src,
                                                        __bf16* __restrict__ dst) {
  int idx = blockIdx.x * 256 + threadIdx.x;
  f32x4 v = ((const f32x4*)src)[idx];
  bf16x4 o;
#pragma unroll
  for (int i = 0; i < 4; ++i) o[i] = (__bf16)v[i];
  ((bf16x4*)dst)[idx] = o;
}

// ---------------- tiled transpose (64x64 tiles, batched via z) ----------------
// src type T (float or __bf16), dst always bf16. dst[c][r] = (bf16)src[r][c].
template <typename T>
__global__ __launch_bounds__(256) void transpose_tiles(const T* __restrict__ src,
                                                       __bf16* __restrict__ dst,
                                                       int R, int C) {
  src += (size_t)blockIdx.z * R * C;
  dst += (size_t)blockIdx.z * R * C;
  __shared__ __bf16 tile[64][65];
  const int r0 = blockIdx.y * 64, c0 = blockIdx.x * 64;
  const int t = threadIdx.x;
  const int col = t & 63, rsub = t >> 6;
#pragma unroll
  for (int i = 0; i < 16; ++i) {
    int r = rsub + i * 4;
    tile[r][col] = (__bf16)src[(size_t)(r0 + r) * C + (c0 + col)];
  }
  __syncthreads();
#pragma unroll
  for (int i = 0; i < 16; ++i) {
    int r = rsub + i * 4;  // row of dst tile == col of src tile
    dst[(size_t)(c0 + r) * R + (r0 + col)] = tile[col][r];
  }
}

// ---------------- GEMM: C = A (M x K) * BT^T, BT is (N x K) row-major ---------
// EPI 0: plain f32 store to Cout (row-major M x Ndim)
// EPI 1: QKV bf16 scatter into per-head (NH, S_LEN, HDIM) buffers
template <int EPI>
__global__ __launch_bounds__(256) void gemm_bt(const __bf16* __restrict__ A,
                                               const __bf16* __restrict__ BT,
                                               __bf16* __restrict__ Cq,
                                               __bf16* __restrict__ Ck,
                                               __bf16* __restrict__ Cv,
                                               float* __restrict__ Cout,
                                               int Kdim, int Ndim) {
  __shared__ __align__(16) __bf16 At[128][40];
  __shared__ __align__(16) __bf16 Bt[128][40];
  const int t = threadIdx.x;
  const int wave = t >> 6, lane = t & 63;
  const int wr = wave >> 1, wc = wave & 1;
  const int lrow = lane & 15, lk = lane >> 4;
  const int bm = blockIdx.x, bn = blockIdx.y;

  f32x4 acc[4][4];
#pragma unroll
  for (int i = 0; i < 4; ++i)
#pragma unroll
    for (int j = 0; j < 4; ++j) acc[i][j] = f32x4{0.f, 0.f, 0.f, 0.f};

  const int arow0 = bm * 128, brow0 = bn * 128;
  for (int k0 = 0; k0 < Kdim; k0 += 32) {
    __syncthreads();
#pragma unroll
    for (int u = 0; u < 2; ++u) {
      int idx = t + u * 256;
      int row = idx >> 2, col = (idx & 3) * 8;
      *(bf16x8*)&At[row][col] =
          *(const bf16x8*)&A[(size_t)(arow0 + row) * Kdim + (k0 + col)];
      *(bf16x8*)&Bt[row][col] =
          *(const bf16x8*)&BT[(size_t)(brow0 + row) * Kdim + (k0 + col)];
    }
    __syncthreads();
    bf16x8 af[4], bfr[4];
#pragma unroll
    for (int mi = 0; mi < 4; ++mi)
      af[mi] = *(const bf16x8*)&At[wr * 64 + mi * 16 + lrow][lk * 8];
#pragma unroll
    for (int ni = 0; ni < 4; ++ni)
      bfr[ni] = *(const bf16x8*)&Bt[wc * 64 + ni * 16 + lrow][lk * 8];
#pragma unroll
    for (int mi = 0; mi < 4; ++mi)
#pragma unroll
      for (int ni = 0; ni < 4; ++ni)
        acc[mi][ni] =
            __builtin_amdgcn_mfma_f32_16x16x32_bf16(af[mi], bfr[ni], acc[mi][ni], 0, 0, 0);
  }

  // C/D layout: row = (lane>>4)*4 + reg, col = lane&15   [m89-verified]
  const int rb = bm * 128 + wr * 64 + lk * 4;
  const int cb = bn * 128 + wc * 64 + lrow;
#pragma unroll
  for (int mi = 0; mi < 4; ++mi)
#pragma unroll
    for (int ni = 0; ni < 4; ++ni) {
      int c = cb + ni * 16;
#pragma unroll
      for (int r = 0; r < 4; ++r) {
        int row = rb + mi * 16 + r;
        float v = acc[mi][ni][r];
        if (EPI == 0) {
          Cout[(size_t)row * Ndim + c] = v;
        } else {
          int type = c >> 10, d = c & 1023;
          int hh = d >> 6, hd = d & 63;
          __bf16* dp = (type == 0) ? Cq : (type == 1) ? Ck : Cv;
          dp[((size_t)hh * S_LEN + row) * HDIM + hd] = (__bf16)v;
        }
      }
    }
}

// ---------------- RoPE in place on (NH, S, HD) Q and K ------------------------
__global__ __launch_bounds__(256) void rope_kernel(__bf16* __restrict__ Q,
                                                   __bf16* __restrict__ Kb,
                                                   const float* __restrict__ freqs) {
  size_t idx = (size_t)blockIdx.x * 256 + threadIdx.x;  // over NH*S*32
  int i = idx & 31;
  size_t rest = idx >> 5;
  int s = rest & 4095;
  int h = (int)(rest >> 12);
  float c = freqs[(s * 32 + i) * 2 + 0];
  float sn = freqs[(s * 32 + i) * 2 + 1];
  size_t base = ((size_t)h * S_LEN + s) * HDIM + 2 * i;
  float qa = (float)Q[base], qb = (float)Q[base + 1];
  Q[base] = (__bf16)(qa * c - qb * sn);
  Q[base + 1] = (__bf16)(qa * sn + qb * c);
  float ka = (float)Kb[base], kb2 = (float)Kb[base + 1];
  Kb[base] = (__bf16)(ka * c - kb2 * sn);
  Kb[base + 1] = (__bf16)(ka * sn + kb2 * c);
}

// ---------------- flash attention: 4 waves x 16 q-rows, KBLK=64 ---------------
__global__ __launch_bounds__(256) void attn_kernel(const __bf16* __restrict__ Q,
                                                   const __bf16* __restrict__ Kmat,
                                                   const __bf16* __restrict__ Vt,
                                                   const float* __restrict__ mask,
                                                   __bf16* __restrict__ AO) {
  const int h = blockIdx.y;
  const int qb = blockIdx.x;
  const int t = threadIdx.x;
  const int wave = t >> 6, lane = t & 63;
  const int lq = lane & 15, lk = lane >> 4;

  __shared__ __align__(16) __bf16 Kt[64][72];
  __shared__ __align__(16) __bf16 Vtl[64][72];
  __shared__ __align__(16) __bf16 Pl[4][16][72];
  __shared__ float maskadd[64];

  const int qrow = qb * 64 + wave * 16 + lq;
  const __bf16* qptr = Q + ((size_t)h * S_LEN + qrow) * HDIM + lk * 8;
  bf16x8 qf0 = *(const bf16x8*)qptr;
  bf16x8 qf1 = *(const bf16x8*)(qptr + 32);
  // fold scaling = HD^-0.5 = 0.125 into Q (power of 2: exact in bf16)
#pragma unroll
  for (int i = 0; i < 8; ++i) {
    qf0[i] = (__bf16)((float)qf0[i] * 0.125f);
    qf1[i] = (__bf16)((float)qf1[i] * 0.125f);
  }

  float m[4], lsum[4];
  f32x4 o[4];
#pragma unroll
  for (int r = 0; r < 4; ++r) { m[r] = -1e30f; lsum[r] = 0.f; }
#pragma unroll
  for (int n = 0; n < 4; ++n) o[n] = f32x4{0.f, 0.f, 0.f, 0.f};

  for (int kb = 0; kb < S_LEN; kb += 64) {
    __syncthreads();
#pragma unroll
    for (int u = 0; u < 2; ++u) {
      int idx = t + u * 256;
      int row = idx >> 3, col = (idx & 7) * 8;
      *(bf16x8*)&Kt[row][col] =
          *(const bf16x8*)&Kmat[((size_t)h * S_LEN + kb + row) * HDIM + col];
      *(bf16x8*)&Vtl[row][col] =
          *(const bf16x8*)&Vt[((size_t)h * HDIM + row) * S_LEN + kb + col];
    }
    if (t < 64) maskadd[t] = (1.0f - mask[kb + t]) * -10000.0f;
    __syncthreads();

    // scores: D[q=4*lk+r][k=j*16+lq]
    f32x4 sf[4];
#pragma unroll
    for (int j = 0; j < 4; ++j) {
      bf16x8 k0 = *(const bf16x8*)&Kt[j * 16 + lq][lk * 8];
      bf16x8 k1 = *(const bf16x8*)&Kt[j * 16 + lq][32 + lk * 8];
      f32x4 z = f32x4{0.f, 0.f, 0.f, 0.f};
      z = __builtin_amdgcn_mfma_f32_16x16x32_bf16(qf0, k0, z, 0, 0, 0);
      z = __builtin_amdgcn_mfma_f32_16x16x32_bf16(qf1, k1, z, 0, 0, 0);
      sf[j] = z;
    }
#pragma unroll
    for (int j = 0; j < 4; ++j) {
      float ma = maskadd[j * 16 + lq];
#pragma unroll
      for (int r = 0; r < 4; ++r) sf[j][r] += ma;
    }

    // online softmax (rows live across 16 lanes: xor 1,2,4,8)
    float alpha[4];
#pragma unroll
    for (int r = 0; r < 4; ++r) {
      float mx = fmaxf(fmaxf(sf[0][r], sf[1][r]), fmaxf(sf[2][r], sf[3][r]));
      mx = fmaxf(mx, __shfl_xor(mx, 1));
      mx = fmaxf(mx, __shfl_xor(mx, 2));
      mx = fmaxf(mx, __shfl_xor(mx, 4));
      mx = fmaxf(mx, __shfl_xor(mx, 8));
      float mn = fmaxf(m[r], mx);
      alpha[r] = exp2f((m[r] - mn) * 1.44269504f);
      float ps = 0.f;
#pragma unroll
      for (int j = 0; j < 4; ++j) {
        float p = exp2f((sf[j][r] - mn) * 1.44269504f);
        sf[j][r] = p;
        ps += p;
      }
      ps += __shfl_xor(ps, 1);
      ps += __shfl_xor(ps, 2);
      ps += __shfl_xor(ps, 4);
      ps += __shfl_xor(ps, 8);
      lsum[r] = lsum[r] * alpha[r] + ps;
      m[r] = mn;
#pragma unroll
      for (int n = 0; n < 4; ++n) o[n][r] *= alpha[r];
    }

    // bounce P through wave-private LDS into MFMA A layout
#pragma unroll
    for (int j = 0; j < 4; ++j)
#pragma unroll
      for (int r = 0; r < 4; ++r)
        Pl[wave][lk * 4 + r][j * 16 + lq] = (__bf16)sf[j][r];
    asm volatile("s_waitcnt lgkmcnt(0)" ::: "memory");

    bf16x8 pa0 = *(const bf16x8*)&Pl[wave][lq][lk * 8];
    bf16x8 pa1 = *(const bf16x8*)&Pl[wave][lq][32 + lk * 8];
#pragma unroll
    for (int n = 0; n < 4; ++n) {
      bf16x8 v0 = *(const bf16x8*)&Vtl[n * 16 + lq][lk * 8];
      bf16x8 v1 = *(const bf16x8*)&Vtl[n * 16 + lq][32 + lk * 8];
      o[n] = __builtin_amdgcn_mfma_f32_16x16x32_bf16(pa0, v0, o[n], 0, 0, 0);
      o[n] = __builtin_amdgcn_mfma_f32_16x16x32_bf16(pa1, v1, o[n], 0, 0, 0);
    }
  }

#pragma unroll
  for (int r = 0; r < 4; ++r) lsum[r] = 1.0f / fmaxf(lsum[r], 1e-30f);
  const int orow = qb * 64 + wave * 16 + lk * 4;
#pragma unroll
  for (int n = 0; n < 4; ++n)
#pragma unroll
    for (int r = 0; r < 4; ++r)
      AO[(size_t)(orow + r) * DMODEL + h * HDIM + n * 16 + lq] =
          (__bf16)(o[n][r] * lsum[r]);
}

// ------------------------------------------------------------------------------
extern "C" void kernel_launch(void* const* d_in, const int* in_sizes, int n_in,
                              void* d_out, int out_size, void* d_ws, size_t ws_size,
                              hipStream_t stream) {
  const float* X = (const float*)d_in[0];
  const float* freqs = (const float*)d_in[1];
  const float* mask = (const float*)d_in[2];
  const float* wq = (const float*)d_in[3];
  const float* wk = (const float*)d_in[4];
  const float* wv = (const float*)d_in[5];
  const float* wo = (const float*)d_in[6];
  float* out = (float*)d_out;

  __bf16* WTqkv = (__bf16*)d_ws;                       // 3072*1024
  __bf16* WoT = WTqkv + 3072 * 1024;                   // 1024*1024
  __bf16* Xb = WoT + 1024 * 1024;                      // 4096*1024
  __bf16* Qb = Xb + (size_t)S_LEN * DMODEL;            // NH*S*HD each
  __bf16* Kb = Qb + (size_t)NH * S_LEN * HDIM;
  __bf16* Vb = Kb + (size_t)NH * S_LEN * HDIM;
  __bf16* Vtb = Vb + (size_t)NH * S_LEN * HDIM;
  __bf16* AO = Vb;  // V raw is dead after V->Vt transpose

  // X -> bf16
  convert_f32_bf16<<<dim3(S_LEN * DMODEL / 1024), 256, 0, stream>>>(X, Xb);

  // weight transposes: WT[n][k] = W[k][n], f32 -> bf16
  transpose_tiles<float><<<dim3(16, 16, 1), 256, 0, stream>>>(wq, WTqkv, 1024, 1024);
  transpose_tiles<float><<<dim3(16, 16, 1), 256, 0, stream>>>(wk, WTqkv + 1024 * 1024, 1024, 1024);
  transpose_tiles<float><<<dim3(16, 16, 1), 256, 0, stream>>>(wv, WTqkv + 2 * 1024 * 1024, 1024, 1024);
  transpose_tiles<float><<<dim3(16, 16, 1), 256, 0, stream>>>(wo, WoT, 1024, 1024);

  // QKV projection with per-head scatter
  gemm_bt<1><<<dim3(32, 24), 256, 0, stream>>>(Xb, WTqkv, Qb, Kb, Vb, nullptr, 1024, 3072);

  // RoPE on Q, K
  rope_kernel<<<dim3((NH * S_LEN * 32) / 256), 256, 0, stream>>>(Qb, Kb, freqs);

  // V -> V^T per head: (S,HD) -> (HD,S)
  transpose_tiles<__bf16><<<dim3(1, 64, NH), 256, 0, stream>>>(Vb, Vtb, S_LEN, HDIM);

  // attention
  attn_kernel<<<dim3(S_LEN / 64, NH), 256, 0, stream>>>(Qb, Kb, Vtb, mask, AO);

  // output projection -> f32 out
  gemm_bt<0><<<dim3(32, 8), 256, 0, stream>>>(AO, WoT, nullptr, nullptr, nullptr, out, 1024, 1024);
}

// Round 5
// 326.154 us; speedup vs baseline: 1.0383x; 1.0383x over previous
//
#include <hip/hip_runtime.h>
#include <stdint.h>

#define S_LEN 4096
#define DMODEL 1024
#define NH 16
#define HDIM 64

typedef __attribute__((ext_vector_type(8))) __bf16 bf16x8;
typedef __attribute__((ext_vector_type(4))) __bf16 bf16x4;
typedef __attribute__((ext_vector_type(2))) __bf16 bf16x2;
typedef __attribute__((ext_vector_type(4))) float f32x4;
typedef __attribute__((ext_vector_type(16))) float f32x16;
typedef __attribute__((ext_vector_type(4))) unsigned int uint32x4;

// ---------------- f32 -> bf16 pack (vectorized) -------------------------------
__global__ __launch_bounds__(256) void convert_f32_bf16(const float* __restrict__ src,
                                                        __bf16* __restrict__ dst) {
  int idx = blockIdx.x * 256 + threadIdx.x;
  f32x4 v = ((const f32x4*)src)[idx];
  bf16x4 o;
#pragma unroll
  for (int i = 0; i < 4; ++i) o[i] = (__bf16)v[i];
  ((bf16x4*)dst)[idx] = o;
}

// ---------------- tiled transpose (64x64 tiles, batched via z) ----------------
template <typename T>
__global__ __launch_bounds__(256) void transpose_tiles(const T* __restrict__ src,
                                                       __bf16* __restrict__ dst,
                                                       int R, int C) {
  src += (size_t)blockIdx.z * R * C;
  dst += (size_t)blockIdx.z * R * C;
  __shared__ __bf16 tile[64][65];
  const int r0 = blockIdx.y * 64, c0 = blockIdx.x * 64;
  const int t = threadIdx.x;
  const int col = t & 63, rsub = t >> 6;
#pragma unroll
  for (int i = 0; i < 16; ++i) {
    int r = rsub + i * 4;
    tile[r][col] = (__bf16)src[(size_t)(r0 + r) * C + (c0 + col)];
  }
  __syncthreads();
#pragma unroll
  for (int i = 0; i < 16; ++i) {
    int r = rsub + i * 4;
    dst[(size_t)(c0 + r) * R + (r0 + col)] = tile[col][r];
  }
}

// ---------------- GEMM: C = A (M x K) * BT^T, BT is (N x K) row-major ---------
template <int EPI>
__global__ __launch_bounds__(256) void gemm_bt(const __bf16* __restrict__ A,
                                               const __bf16* __restrict__ BT,
                                               __bf16* __restrict__ Cq,
                                               __bf16* __restrict__ Ck,
                                               __bf16* __restrict__ Cv,
                                               float* __restrict__ Cout,
                                               int Kdim, int Ndim) {
  __shared__ __align__(16) __bf16 At[128][40];
  __shared__ __align__(16) __bf16 Bt[128][40];
  const int t = threadIdx.x;
  const int wave = t >> 6, lane = t & 63;
  const int wr = wave >> 1, wc = wave & 1;
  const int lrow = lane & 15, lk = lane >> 4;
  const int bm = blockIdx.x, bn = blockIdx.y;

  f32x4 acc[4][4];
#pragma unroll
  for (int i = 0; i < 4; ++i)
#pragma unroll
    for (int j = 0; j < 4; ++j) acc[i][j] = f32x4{0.f, 0.f, 0.f, 0.f};

  const int arow0 = bm * 128, brow0 = bn * 128;
  for (int k0 = 0; k0 < Kdim; k0 += 32) {
    __syncthreads();
#pragma unroll
    for (int u = 0; u < 2; ++u) {
      int idx = t + u * 256;
      int row = idx >> 2, col = (idx & 3) * 8;
      *(bf16x8*)&At[row][col] =
          *(const bf16x8*)&A[(size_t)(arow0 + row) * Kdim + (k0 + col)];
      *(bf16x8*)&Bt[row][col] =
          *(const bf16x8*)&BT[(size_t)(brow0 + row) * Kdim + (k0 + col)];
    }
    __syncthreads();
    bf16x8 af[4], bfr[4];
#pragma unroll
    for (int mi = 0; mi < 4; ++mi)
      af[mi] = *(const bf16x8*)&At[wr * 64 + mi * 16 + lrow][lk * 8];
#pragma unroll
    for (int ni = 0; ni < 4; ++ni)
      bfr[ni] = *(const bf16x8*)&Bt[wc * 64 + ni * 16 + lrow][lk * 8];
#pragma unroll
    for (int mi = 0; mi < 4; ++mi)
#pragma unroll
      for (int ni = 0; ni < 4; ++ni)
        acc[mi][ni] =
            __builtin_amdgcn_mfma_f32_16x16x32_bf16(af[mi], bfr[ni], acc[mi][ni], 0, 0, 0);
  }

  const int rb = bm * 128 + wr * 64 + lk * 4;
  const int cb = bn * 128 + wc * 64 + lrow;
#pragma unroll
  for (int mi = 0; mi < 4; ++mi)
#pragma unroll
    for (int ni = 0; ni < 4; ++ni) {
      int c = cb + ni * 16;
#pragma unroll
      for (int r = 0; r < 4; ++r) {
        int row = rb + mi * 16 + r;
        float v = acc[mi][ni][r];
        if (EPI == 0) {
          Cout[(size_t)row * Ndim + c] = v;
        } else {
          int type = c >> 10, d = c & 1023;
          int hh = d >> 6, hd = d & 63;
          __bf16* dp = (type == 0) ? Cq : (type == 1) ? Ck : Cv;
          dp[((size_t)hh * S_LEN + row) * HDIM + hd] = (__bf16)v;
        }
      }
    }
}

// ---------------- RoPE in place on (NH, S, HD) Q and K ------------------------
__global__ __launch_bounds__(256) void rope_kernel(__bf16* __restrict__ Q,
                                                   __bf16* __restrict__ Kb,
                                                   const float* __restrict__ freqs) {
  size_t idx = (size_t)blockIdx.x * 256 + threadIdx.x;
  int i = idx & 31;
  size_t rest = idx >> 5;
  int s = rest & 4095;
  int h = (int)(rest >> 12);
  float c = freqs[(s * 32 + i) * 2 + 0];
  float sn = freqs[(s * 32 + i) * 2 + 1];
  size_t base = ((size_t)h * S_LEN + s) * HDIM + 2 * i;
  float qa = (float)Q[base], qb = (float)Q[base + 1];
  Q[base] = (__bf16)(qa * c - qb * sn);
  Q[base + 1] = (__bf16)(qa * sn + qb * c);
  float ka = (float)Kb[base], kb2 = (float)Kb[base + 1];
  Kb[base] = (__bf16)(ka * c - kb2 * sn);
  Kb[base + 1] = (__bf16)(ka * sn + kb2 * c);
}

// ---------------- flash attention: swapped-QK^T, 32x32x16, no in-loop barriers
__global__ __launch_bounds__(256, 2) void attn_kernel(const __bf16* __restrict__ Q,
                                                      const __bf16* __restrict__ Kmat,
                                                      const __bf16* __restrict__ Vt,
                                                      const float* __restrict__ mask,
                                                      __bf16* __restrict__ AO) {
  __shared__ float maskL[S_LEN];
  const int t = threadIdx.x;
  const int id = blockIdx.x;                    // 0..511
  const int swz = (id & 7) * 64 + (id >> 3);    // 512 = 8*64: bijective
  const int h = swz >> 5;
  const int qb = swz & 31;
  const int wave = t >> 6, lane = t & 63;
  const int lq = lane & 31, hi = lane >> 5;

  // stage mask-add once (only barrier in the kernel)
#pragma unroll
  for (int i = 0; i < 16; ++i) {
    int idx = t + i * 256;
    maskL[idx] = (1.0f - mask[idx]) * -10000.0f;
  }
  __syncthreads();

  // Q fragments (B-operand): lane holds col q = lq, k-dim d = ds*16 + hi*8 + e
  const __bf16* Qh = Q + ((size_t)h * S_LEN + qb * 128 + wave * 32 + lq) * HDIM;
  bf16x8 qf[4];
#pragma unroll
  for (int ds = 0; ds < 4; ++ds) {
    qf[ds] = *(const bf16x8*)(Qh + ds * 16 + hi * 8);
#pragma unroll
    for (int e = 0; e < 8; ++e) qf[ds][e] = (__bf16)((float)qf[ds][e] * 0.125f);
  }

  const __bf16* Kh = Kmat + (size_t)h * S_LEN * HDIM;
  const __bf16* Vh = Vt + (size_t)h * HDIM * S_LEN;

  float m = -1e30f, l = 0.f;
  f32x16 o0, o1;
#pragma unroll
  for (int r = 0; r < 16; ++r) { o0[r] = 0.f; o1[r] = 0.f; }

  for (int kb = 0; kb < S_LEN; kb += 64) {
    // ---- QK^T swapped: p[r] = S[k = kb + (r&3)+8*(r>>2)+4*hi][q = lq]
    f32x16 p0, p1;
#pragma unroll
    for (int r = 0; r < 16; ++r) { p0[r] = 0.f; p1[r] = 0.f; }
#pragma unroll
    for (int ds = 0; ds < 4; ++ds) {
      bf16x8 kf0 = *(const bf16x8*)(Kh + (size_t)(kb + lq) * HDIM + ds * 16 + hi * 8);
      p0 = __builtin_amdgcn_mfma_f32_32x32x16_bf16(kf0, qf[ds], p0, 0, 0, 0);
    }
#pragma unroll
    for (int ds = 0; ds < 4; ++ds) {
      bf16x8 kf1 = *(const bf16x8*)(Kh + (size_t)(kb + 32 + lq) * HDIM + ds * 16 + hi * 8);
      p1 = __builtin_amdgcn_mfma_f32_32x32x16_bf16(kf1, qf[ds], p1, 0, 0, 0);
    }

    // ---- mask add (broadcast f32x4 LDS reads)
#pragma unroll
    for (int tq = 0; tq < 4; ++tq) {
      f32x4 ma0 = *(const f32x4*)&maskL[kb + tq * 8 + hi * 4];
      f32x4 ma1 = *(const f32x4*)&maskL[kb + 32 + tq * 8 + hi * 4];
#pragma unroll
      for (int c = 0; c < 4; ++c) {
        p0[tq * 4 + c] += ma0[c];
        p1[tq * 4 + c] += ma1[c];
      }
    }

    // ---- online softmax: per-lane over 32 vals + one xor-32 shuffle each
    float mx = p0[0];
#pragma unroll
    for (int r = 1; r < 16; ++r) mx = fmaxf(mx, p0[r]);
#pragma unroll
    for (int r = 0; r < 16; ++r) mx = fmaxf(mx, p1[r]);
    mx = fmaxf(mx, __shfl_xor(mx, 32));
    float mn = fmaxf(m, mx);
    float alpha = exp2f((m - mn) * 1.44269504f);
    m = mn;
    float ps = 0.f;
#pragma unroll
    for (int r = 0; r < 16; ++r) {
      float pe = exp2f((p0[r] - mn) * 1.44269504f);
      p0[r] = pe;
      ps += pe;
    }
#pragma unroll
    for (int r = 0; r < 16; ++r) {
      float pe = exp2f((p1[r] - mn) * 1.44269504f);
      p1[r] = pe;
      ps += pe;
    }
    ps += __shfl_xor(ps, 32);
    l = l * alpha + ps;
#pragma unroll
    for (int r = 0; r < 16; ++r) { o0[r] *= alpha; o1[r] *= alpha; }

    // ---- pack P to bf16 pairs: tt[tp] holds k = 8*(tp>>1) + 4*hi + (2tp&3)+{0,1}
    unsigned int tt0[8], tt1[8];
#pragma unroll
    for (int tp = 0; tp < 8; ++tp) {
      bf16x2 w0, w1;
      w0[0] = (__bf16)p0[2 * tp]; w0[1] = (__bf16)p0[2 * tp + 1];
      w1[0] = (__bf16)p1[2 * tp]; w1[1] = (__bf16)p1[2 * tp + 1];
      tt0[tp] = __builtin_bit_cast(unsigned int, w0);
      tt1[tp] = __builtin_bit_cast(unsigned int, w1);
    }

    // ---- build PV B-fragments via shfl_xor(32) + select (unambiguous semantics).
    // Within a 32-k group, lane (lq,hi) has: b_g = pair k = 8g + 4hi + {0,1}
    //                                        (g even slot) / +{2,3} (odd slot pair b_{g+1}).
    // Frag dword s needs pair k = 8*hi + 2s + {0,1}:
    //   s=0: hi0->b0(own)        hi1->b2(partner, via shfl_xor 32)
    //   s=1: hi0->b1(own)        hi1->b3(partner)
    //   s=2: hi0->b0(partner)    hi1->b2(own)
    //   s=3: hi0->b1(partner)    hi1->b3(own)
#pragma unroll
    for (int ks = 0; ks < 4; ++ks) {
      unsigned int b0, b1, b2, b3;
      if (ks == 0)      { b0 = tt0[0]; b1 = tt0[1]; b2 = tt0[2]; b3 = tt0[3]; }
      else if (ks == 1) { b0 = tt0[4]; b1 = tt0[5]; b2 = tt0[6]; b3 = tt0[7]; }
      else if (ks == 2) { b0 = tt1[0]; b1 = tt1[1]; b2 = tt1[2]; b3 = tt1[3]; }
      else              { b0 = tt1[4]; b1 = tt1[5]; b2 = tt1[6]; b3 = tt1[7]; }
      unsigned int x0 = (unsigned int)__shfl_xor((int)b0, 32);
      unsigned int x1 = (unsigned int)__shfl_xor((int)b1, 32);
      unsigned int x2 = (unsigned int)__shfl_xor((int)b2, 32);
      unsigned int x3 = (unsigned int)__shfl_xor((int)b3, 32);
      uint32x4 pb;
      pb[0] = hi ? x2 : b0;
      pb[1] = hi ? x3 : b1;
      pb[2] = hi ? b2 : x0;
      pb[3] = hi ? b3 : x1;
      bf16x8 pbv = __builtin_bit_cast(bf16x8, pb);
      bf16x8 v0 = *(const bf16x8*)(Vh + (size_t)(0 + lq) * S_LEN + kb + ks * 16 + hi * 8);
      bf16x8 v1 = *(const bf16x8*)(Vh + (size_t)(32 + lq) * S_LEN + kb + ks * 16 + hi * 8);
      o0 = __builtin_amdgcn_mfma_f32_32x32x16_bf16(v0, pbv, o0, 0, 0, 0);
      o1 = __builtin_amdgcn_mfma_f32_32x32x16_bf16(v1, pbv, o1, 0, 0, 0);
    }
  }

  // ---- epilogue: normalize and store; d = 8*tq + 4*hi + c, q = lq
  float inv = 1.0f / fmaxf(l, 1e-30f);
  __bf16* aorow = AO + (size_t)(qb * 128 + wave * 32 + lq) * DMODEL + h * HDIM;
#pragma unroll
  for (int tq = 0; tq < 4; ++tq) {
    bf16x4 ov0, ov1;
#pragma unroll
    for (int c = 0; c < 4; ++c) {
      ov0[c] = (__bf16)(o0[tq * 4 + c] * inv);
      ov1[c] = (__bf16)(o1[tq * 4 + c] * inv);
    }
    *(bf16x4*)(aorow + tq * 8 + hi * 4) = ov0;
    *(bf16x4*)(aorow + 32 + tq * 8 + hi * 4) = ov1;
  }
}

// ------------------------------------------------------------------------------
extern "C" void kernel_launch(void* const* d_in, const int* in_sizes, int n_in,
                              void* d_out, int out_size, void* d_ws, size_t ws_size,
                              hipStream_t stream) {
  const float* X = (const float*)d_in[0];
  const float* freqs = (const float*)d_in[1];
  const float* mask = (const float*)d_in[2];
  const float* wq = (const float*)d_in[3];
  const float* wk = (const float*)d_in[4];
  const float* wv = (const float*)d_in[5];
  const float* wo = (const float*)d_in[6];
  float* out = (float*)d_out;

  __bf16* WTqkv = (__bf16*)d_ws;                       // 3072*1024
  __bf16* WoT = WTqkv + 3072 * 1024;                   // 1024*1024
  __bf16* Xb = WoT + 1024 * 1024;                      // 4096*1024
  __bf16* Qb = Xb + (size_t)S_LEN * DMODEL;
  __bf16* Kb = Qb + (size_t)NH * S_LEN * HDIM;
  __bf16* Vb = Kb + (size_t)NH * S_LEN * HDIM;
  __bf16* Vtb = Vb + (size_t)NH * S_LEN * HDIM;
  __bf16* AO = Vb;  // V raw is dead after V->Vt transpose

  convert_f32_bf16<<<dim3(S_LEN * DMODEL / 1024), 256, 0, stream>>>(X, Xb);

  transpose_tiles<float><<<dim3(16, 16, 1), 256, 0, stream>>>(wq, WTqkv, 1024, 1024);
  transpose_tiles<float><<<dim3(16, 16, 1), 256, 0, stream>>>(wk, WTqkv + 1024 * 1024, 1024, 1024);
  transpose_tiles<float><<<dim3(16, 16, 1), 256, 0, stream>>>(wv, WTqkv + 2 * 1024 * 1024, 1024, 1024);
  transpose_tiles<float><<<dim3(16, 16, 1), 256, 0, stream>>>(wo, WoT, 1024, 1024);

  gemm_bt<1><<<dim3(32, 24), 256, 0, stream>>>(Xb, WTqkv, Qb, Kb, Vb, nullptr, 1024, 3072);

  rope_kernel<<<dim3((NH * S_LEN * 32) / 256), 256, 0, stream>>>(Qb, Kb, freqs);

  transpose_tiles<__bf16><<<dim3(1, 64, NH), 256, 0, stream>>>(Vb, Vtb, S_LEN, HDIM);

  attn_kernel<<<dim3(512), 256, 0, stream>>>(Qb, Kb, Vtb, mask, AO);

  gemm_bt<0><<<dim3(32, 8), 256, 0, stream>>>(AO, WoT, nullptr, nullptr, nullptr, out, 1024, 1024);
}